// Round 6
// baseline (1369.669 us; speedup 1.0000x reference)
//
#include <hip/hip_runtime.h>

// Fused windowed multi-head attention for MI355X (gfx950).
// B=8192 windows, N=49 tokens, C=192, H=6 heads, HD=32.
// Inputs/outputs are FP32 (per reference); mask int32. Interior compute bf16 MFMA.
//
// Structure (v6): persistent-ish blocks. 1024 blocks x 384 threads (6 waves,
// one per head); each block loops over 8 consecutive windows with a
// double-buffered x tile and cross-window prefetch:
//   loop top:   issue global loads of x(i+1)+mask(i+1) into registers
//   compute(i): phases 2a/2b/4/5 on xbuf[cur] (wave-local, no barriers)
//   barrier     (all reads of xbuf[cur] done)
//   writes:     O_all -> xbuf[cur] (overlay) ; staged x(i+1) -> xbuf[cur^1]
//   barrier     (O_all + stage visible)
//   phase 6:    proj GEMM from xbuf[cur], out stores (drain under next window)
//
// Why: rounds 1-5 showed HW co-schedules exactly ONE workgroup per CU for this
// kernel regardless of LDS (89.6/74.2/50.7 KB) or VGPR (128/88/84); v5 doubled
// resident waves (12-wave WG, occupancy 17.8->35%) with ZERO time change ->
// waves stall in barrier-synchronized convoys; residency is not the lever.
// The stalls are x-stage HBM latency + end-of-kernel store drain, serialized
// per 16.3 us block. v6 overlaps them with the previous/next window's compute
// inside one workgroup (prefetch pipeline), 2 barriers per window.
//
// Per-window phases (unchanged math from v4):
//   2a: Q,K GEMM swapped operands mfma(W,X) -> Q^T/K^T C-layout, collapsed to
//       bf16 fragments via in-register quad-shuffle xpose (no q/k LDS).
//   2b: V GEMM normal operands, v^T -> per-head swizzled LDS.
//   4:  per-column-tile fused { S^T slice = mfma(K,Q); masked softmax
//       (lane-local q-rows, 2 shfl_xor); xpose -> P A-fragment } (no s/p LDS).
//   5:  O = P V (v^T from LDS as B operand).
//   6:  O tile (64x192) via LDS, cooperative projection GEMM + bias, store.
//
// Weights repacked each call fp32 -> bf16 in B-fragment-contiguous layout:
// wp[(kt*COLS + col)*32 + kk] = w[(kt*32+kk)*COLS + col].

typedef __attribute__((ext_vector_type(8))) short short8;
typedef __attribute__((ext_vector_type(4))) float f32x4;

#define SCALE 0.17677669529663687f   // 32^-0.5
#define WPB   8                      // windows per block

__device__ __forceinline__ unsigned short f2bf(float x) {
    union { float f; unsigned int i; } v; v.f = x;
    return (unsigned short)((v.i + 0x7FFFu + ((v.i >> 16) & 1u)) >> 16);
}

// packed f32x2 -> bf16x2 (RNE), 1 instr
__device__ __forceinline__ unsigned int pkbf(float lo, float hi) {
    unsigned int r;
    asm("v_cvt_pk_bf16_f32 %0, %1, %2" : "=v"(r) : "v"(lo), "v"(hi));
    return r;
}

// XOR-swizzled index into a [R][64]-short buffer (row stride 128B = 8 x 16B slots).
__device__ __forceinline__ int swz64(int row, int col) {
    return row * 64 + ((((col >> 3) ^ (row & 7)) << 3) | (col & 7));
}

// C-layout pair (two 16-row tiles: tlo = dims/k 0..15, thi = 16..31) ->
// A/B MFMA fragment. dst lane (quad,l16) elem e needs src reg r=e&3 from
// lane ((quad&1)*2 + (e>>2))*16 + l16, tile selected by quad>>1.
__device__ __forceinline__ short8 xpose(f32x4 tlo, f32x4 thi, int srcA, bool hi) {
    unsigned int pl0 = pkbf(tlo[0], tlo[1]);
    unsigned int pl1 = pkbf(tlo[2], tlo[3]);
    unsigned int ph0 = pkbf(thi[0], thi[1]);
    unsigned int ph1 = pkbf(thi[2], thi[3]);
    unsigned int a0 = (unsigned int)__shfl((int)pl0, srcA);
    unsigned int b0 = (unsigned int)__shfl((int)ph0, srcA);
    unsigned int a1 = (unsigned int)__shfl((int)pl1, srcA);
    unsigned int b1 = (unsigned int)__shfl((int)ph1, srcA);
    unsigned int a2 = (unsigned int)__shfl((int)pl0, srcA + 16);
    unsigned int b2 = (unsigned int)__shfl((int)ph0, srcA + 16);
    unsigned int a3 = (unsigned int)__shfl((int)pl1, srcA + 16);
    unsigned int b3 = (unsigned int)__shfl((int)ph1, srcA + 16);
    union { short8 s8; unsigned int u[4]; } f;
    f.u[0] = hi ? b0 : a0;
    f.u[1] = hi ? b1 : a1;
    f.u[2] = hi ? b2 : a2;
    f.u[3] = hi ? b3 : a3;
    return f.s8;
}

__global__ void repack_kernel(const float* __restrict__ wqkv,
                              const float* __restrict__ wproj,
                              unsigned short* __restrict__ wq_pack,
                              unsigned short* __restrict__ wp_pack) {
    int idx = blockIdx.x * 256 + threadIdx.x;
    if (idx < 6 * 576 * 32) {
        int kk  = idx & 31;
        int col = (idx >> 5) % 576;
        int kt  = idx / (576 * 32);
        wq_pack[idx] = f2bf(wqkv[(kt * 32 + kk) * 576 + col]);
    } else {
        int j = idx - 6 * 576 * 32;
        if (j < 6 * 192 * 32) {
            int kk  = j & 31;
            int col = (j >> 5) % 192;
            int kt  = j / (192 * 32);
            wp_pack[j] = f2bf(wproj[(kt * 32 + kk) * 192 + col]);
        }
    }
}

__global__ __launch_bounds__(384)
void win_attn_kernel(const float* __restrict__ x,
                     const int* __restrict__ mask,
                     const float* __restrict__ bqkv,
                     const float* __restrict__ bproj,
                     const unsigned short* __restrict__ wq,
                     const unsigned short* __restrict__ wpj,
                     float* __restrict__ out) {
    // xbuf[c]: 64x200 bf16 x tile of the current window; overlaid by O_all
    //          for phase 6 of the same window while xbuf[c^1] receives the
    //          next window's staged x.
    // vtl[h] : per-head v^T [32][64] swizzled; wave-local across the loop.
    __shared__ __align__(16) unsigned short xbuf[2][12800];
    __shared__ __align__(16) unsigned short vtl[6][2048];
    __shared__ __align__(16) float mbias[2][64];

    const int tid  = threadIdx.x;
    const int lane = tid & 63;
    const int h    = tid >> 6;      // wave index == head
    const int quad = lane >> 4;
    const int l16  = lane & 15;
    const int b0   = blockIdx.x * WPB;

    const int  srcA = ((lane & 16) << 1) | l16;   // ((quad&1)*2)*16 + l16
    const bool hiq  = (lane & 32) != 0;           // quad>>1

    int colb[6];
    #pragma unroll
    for (int t = 0; t < 6; ++t) colb[t] = (t >> 1) * 192 + h * 32 + (t & 1) * 16;

    unsigned short* vtb = &vtl[h][0];

    // ---------------- prologue: stage window b0 into xbuf[0] --------------
    {
        const float* xb = x + (size_t)b0 * 9408;
        for (int i4 = tid; i4 < 2352; i4 += 384) {   // 9408 elems / 4
            int flat = i4 * 4;
            int n = flat / 192, c = flat % 192;      // 192 % 4 == 0
            float4 v = *(const float4*)(const void*)&xb[flat];
            uint2 pk;
            pk.x = pkbf(v.x, v.y);
            pk.y = pkbf(v.z, v.w);
            *(uint2*)(void*)&xbuf[0][n * 200 + c] = pk;
        }
        if (tid < 375) {                             // zero rows 49..63
            uint4 z = {0u, 0u, 0u, 0u};
            *(uint4*)(void*)&xbuf[0][9800 + tid * 8] = z;
        }
        if (tid < 64)
            mbias[0][tid] = (tid < 49 && mask[b0 * 49 + tid] != 0) ? 0.0f
                                                                   : -1e30f;
    }
    __syncthreads();

    int cur = 0;
    for (int wi = 0; wi < WPB; ++wi, cur ^= 1) {
        const int b = b0 + wi;
        const bool more = (wi + 1 < WPB);

        // ---- issue next window's loads (consumed after post-compute bar) --
        float4 st[6];
        float4 st6 = {0.f, 0.f, 0.f, 0.f};
        int mv = 0;
        if (more) {
            const float* xn = x + (size_t)(b + 1) * 9408;
            #pragma unroll
            for (int k = 0; k < 6; ++k)
                st[k] = *(const float4*)(const void*)&xn[(tid + k * 384) * 4];
            if (tid < 48)
                st6 = *(const float4*)(const void*)&xn[(2304 + tid) * 4];
            if (tid < 49)
                mv = mask[(b + 1) * 49 + tid];
        }

        unsigned short* rg  = &xbuf[cur][0];
        float*          mbp = &mbias[cur][0];

        // ---------------- phase 2a: Q,K GEMM (swapped operands) -----------
        short8 qf[4], kf[4];
        {
            f32x4 acc[4][4];
            #pragma unroll
            for (int t = 0; t < 4; ++t)
                #pragma unroll
                for (int mt = 0; mt < 4; ++mt)
                    acc[t][mt] = (f32x4){0.f, 0.f, 0.f, 0.f};

            #pragma unroll
            for (int kt = 0; kt < 6; ++kt) {
                short8 af[4];
                #pragma unroll
                for (int mt = 0; mt < 4; ++mt)
                    af[mt] = *(const short8*)(const void*)
                             &rg[(mt * 16 + l16) * 200 + kt * 32 + quad * 8];
                #pragma unroll
                for (int t = 0; t < 4; ++t) {
                    short8 bw = *(const short8*)(const void*)
                                &wq[(size_t)(kt * 576 + colb[t] + l16) * 32 + quad * 8];
                    #pragma unroll
                    for (int mt = 0; mt < 4; ++mt)
                        acc[t][mt] = __builtin_amdgcn_mfma_f32_16x16x32_bf16(
                                         bw, af[mt], acc[t][mt], 0, 0, 0);
                }
            }
            #pragma unroll
            for (int t = 0; t < 4; ++t) {
                f32x4 bq = *(const f32x4*)(const void*)&bqkv[colb[t] + quad * 4];
                #pragma unroll
                for (int nt = 0; nt < 4; ++nt)
                    #pragma unroll
                    for (int r = 0; r < 4; ++r)
                        acc[t][nt][r] += bq[r];
            }
            #pragma unroll
            for (int nt = 0; nt < 4; ++nt) {
                qf[nt] = xpose(acc[0][nt], acc[1][nt], srcA, hiq);
                kf[nt] = xpose(acc[2][nt], acc[3][nt], srcA, hiq);
            }
        }

        // ---------------- phase 2b: V GEMM + vt -> LDS --------------------
        {
            f32x4 accv[2][4];
            #pragma unroll
            for (int t = 0; t < 2; ++t)
                #pragma unroll
                for (int mt = 0; mt < 4; ++mt)
                    accv[t][mt] = (f32x4){0.f, 0.f, 0.f, 0.f};

            #pragma unroll
            for (int kt = 0; kt < 6; ++kt) {
                short8 af[4];
                #pragma unroll
                for (int mt = 0; mt < 4; ++mt)
                    af[mt] = *(const short8*)(const void*)
                             &rg[(mt * 16 + l16) * 200 + kt * 32 + quad * 8];
                #pragma unroll
                for (int t = 0; t < 2; ++t) {
                    short8 bw = *(const short8*)(const void*)
                                &wq[(size_t)(kt * 576 + colb[4 + t] + l16) * 32 + quad * 8];
                    #pragma unroll
                    for (int mt = 0; mt < 4; ++mt)
                        accv[t][mt] = __builtin_amdgcn_mfma_f32_16x16x32_bf16(
                                          af[mt], bw, accv[t][mt], 0, 0, 0);
                }
            }
            #pragma unroll
            for (int t = 0; t < 2; ++t) {
                float bv = bqkv[colb[4 + t] + l16];
                #pragma unroll
                for (int mt = 0; mt < 4; ++mt) {
                    int d = t * 16 + l16;
                    uint2 pk;
                    pk.x = pkbf(accv[t][mt][0] + bv, accv[t][mt][1] + bv);
                    pk.y = pkbf(accv[t][mt][2] + bv, accv[t][mt][3] + bv);
                    *(uint2*)(void*)&vtb[swz64(d, mt * 16 + quad * 4)] = pk;
                }
            }
        }
        // vt is wave-local and in-order within the wave -> no barrier.

        // ---------------- phase 4: per-slice S^T + softmax + P-frag -------
        f32x4 mb4[4];
        #pragma unroll
        for (int mt = 0; mt < 4; ++mt)
            mb4[mt] = *(const f32x4*)(const void*)&mbp[mt * 16 + quad * 4];

        short8 ap[4][2];
        #pragma unroll
        for (int nt = 0; nt < 4; ++nt) {
            f32x4 sr[4];
            #pragma unroll
            for (int mt = 0; mt < 4; ++mt) {
                sr[mt] = (f32x4){0.f, 0.f, 0.f, 0.f};
                sr[mt] = __builtin_amdgcn_mfma_f32_16x16x32_bf16(
                             kf[mt], qf[nt], sr[mt], 0, 0, 0);
            }
            float pm[4];
            #pragma unroll
            for (int mt = 0; mt < 4; ++mt) {
                #pragma unroll
                for (int r = 0; r < 4; ++r)
                    sr[mt][r] = sr[mt][r] * SCALE + mb4[mt][r];
                pm[mt] = fmaxf(fmaxf(sr[mt][0], sr[mt][1]),
                               fmaxf(sr[mt][2], sr[mt][3]));
            }
            float mx = fmaxf(fmaxf(pm[0], pm[1]), fmaxf(pm[2], pm[3]));
            mx = fmaxf(mx, __shfl_xor(mx, 16));
            mx = fmaxf(mx, __shfl_xor(mx, 32));
            float ps[4];
            #pragma unroll
            for (int mt = 0; mt < 4; ++mt) {
                #pragma unroll
                for (int r = 0; r < 4; ++r)
                    sr[mt][r] = __expf(sr[mt][r] - mx);
                ps[mt] = (sr[mt][0] + sr[mt][1]) + (sr[mt][2] + sr[mt][3]);
            }
            float sum = (ps[0] + ps[1]) + (ps[2] + ps[3]);
            sum += __shfl_xor(sum, 16);
            sum += __shfl_xor(sum, 32);
            float inv = 1.0f / sum;
            #pragma unroll
            for (int mt = 0; mt < 4; ++mt)
                #pragma unroll
                for (int r = 0; r < 4; ++r)
                    sr[mt][r] *= inv;
            ap[nt][0] = xpose(sr[0], sr[1], srcA, hiq);
            ap[nt][1] = xpose(sr[2], sr[3], srcA, hiq);
        }

        // ---------------- phase 5: O = P V --------------------------------
        f32x4 o[4][2];
        #pragma unroll
        for (int mo = 0; mo < 4; ++mo)
            #pragma unroll
            for (int dt = 0; dt < 2; ++dt)
                o[mo][dt] = (f32x4){0.f, 0.f, 0.f, 0.f};

        #pragma unroll
        for (int kt = 0; kt < 2; ++kt) {
            short8 bvv[2];
            #pragma unroll
            for (int dt = 0; dt < 2; ++dt)
                bvv[dt] = *(const short8*)(const void*)
                          &vtb[swz64(dt * 16 + l16, kt * 32 + quad * 8)];
            #pragma unroll
            for (int mo = 0; mo < 4; ++mo)
                #pragma unroll
                for (int dt = 0; dt < 2; ++dt)
                    o[mo][dt] = __builtin_amdgcn_mfma_f32_16x16x32_bf16(
                                    ap[mo][kt], bvv[dt], o[mo][dt], 0, 0, 0);
        }

        __syncthreads();   // all reads of xbuf[cur] done (whole block)

        // ---- O_all -> xbuf[cur] (overlay) --------------------------------
        #pragma unroll
        for (int dt = 0; dt < 2; ++dt)
            #pragma unroll
            for (int mt = 0; mt < 4; ++mt)
                #pragma unroll
                for (int r = 0; r < 4; ++r)
                    rg[(mt * 16 + quad * 4 + r) * 200 + h * 32 + dt * 16 + l16]
                        = f2bf(o[mt][dt][r]);

        // ---- staged x(i+1) -> xbuf[cur^1] --------------------------------
        if (more) {
            unsigned short* nb = &xbuf[cur ^ 1][0];
            #pragma unroll
            for (int k = 0; k < 6; ++k) {
                int flat = (tid + k * 384) * 4;
                int n = flat / 192, c = flat % 192;
                uint2 pk;
                pk.x = pkbf(st[k].x, st[k].y);
                pk.y = pkbf(st[k].z, st[k].w);
                *(uint2*)(void*)&nb[n * 200 + c] = pk;
            }
            if (tid < 48) {
                int flat = (2304 + tid) * 4;
                int n = flat / 192, c = flat % 192;
                uint2 pk;
                pk.x = pkbf(st6.x, st6.y);
                pk.y = pkbf(st6.z, st6.w);
                *(uint2*)(void*)&nb[n * 200 + c] = pk;
            }
            if (tid < 375) {                         // re-zero rows 49..63
                uint4 z = {0u, 0u, 0u, 0u};
                *(uint4*)(void*)&nb[9800 + tid * 8] = z;
            }
            if (tid < 64)
                mbias[cur ^ 1][tid] = (tid < 49 && mv != 0) ? 0.0f : -1e30f;
        }

        __syncthreads();   // O_all + staged x visible

        // ---------------- phase 6: projection GEMM + bias + store ---------
        f32x4 po[2][4];
        #pragma unroll
        for (int nt = 0; nt < 2; ++nt)
            #pragma unroll
            for (int mt = 0; mt < 4; ++mt)
                po[nt][mt] = (f32x4){0.f, 0.f, 0.f, 0.f};

        #pragma unroll
        for (int kt = 0; kt < 6; ++kt) {
            short8 ao[4];
            #pragma unroll
            for (int mt = 0; mt < 4; ++mt)
                ao[mt] = *(const short8*)(const void*)
                         &rg[(mt * 16 + l16) * 200 + kt * 32 + quad * 8];
            #pragma unroll
            for (int nt = 0; nt < 2; ++nt) {
                int col = h * 32 + nt * 16 + l16;
                short8 bw = *(const short8*)(const void*)
                            &wpj[(size_t)(kt * 192 + col) * 32 + quad * 8];
                #pragma unroll
                for (int mt = 0; mt < 4; ++mt)
                    po[nt][mt] = __builtin_amdgcn_mfma_f32_16x16x32_bf16(
                                     ao[mt], bw, po[nt][mt], 0, 0, 0);
            }
        }

        #pragma unroll
        for (int nt = 0; nt < 2; ++nt) {
            int col = h * 32 + nt * 16 + l16;
            float bv = bproj[col];
            #pragma unroll
            for (int mt = 0; mt < 4; ++mt)
                #pragma unroll
                for (int r = 0; r < 4; ++r) {
                    int row = mt * 16 + quad * 4 + r;
                    if (row < 49)
                        out[(size_t)b * 9408 + row * 192 + col]
                            = po[nt][mt][r] + bv;
                }
        }
        // out stores drain during the next window's compute (no wait here).
    }
}

extern "C" void kernel_launch(void* const* d_in, const int* in_sizes, int n_in,
                              void* d_out, int out_size, void* d_ws, size_t ws_size,
                              hipStream_t stream) {
    const float* x      = (const float*)d_in[0];
    const int*   mask   = (const int*)d_in[1];
    const float* w_qkv  = (const float*)d_in[2];
    const float* b_qkv  = (const float*)d_in[3];
    const float* w_proj = (const float*)d_in[4];
    const float* b_proj = (const float*)d_in[5];
    float*       out    = (float*)d_out;

    unsigned short* wq_pack = (unsigned short*)d_ws;          // 110592 elems
    unsigned short* wp_pack = wq_pack + 110592;               //  36864 elems

    repack_kernel<<<(110592 + 36864 + 255) / 256, 256, 0, stream>>>(
        w_qkv, w_proj, wq_pack, wp_pack);
    win_attn_kernel<<<8192 / WPB, 384, 0, stream>>>(x, mask, b_qkv, b_proj,
                                                    wq_pack, wp_pack, out);
}

// Round 10
// 834.084 us; speedup vs baseline: 1.6421x; 1.6421x over previous
//
#include <hip/hip_runtime.h>

// Fused windowed multi-head attention for MI355X (gfx950).
// B=8192 windows, N=49 tokens, C=192, H=6 heads, HD=32.
// Inputs/outputs are FP32 (per reference); mask int32. Interior compute bf16 MFMA.
//
// Structure (v9): 1 block per window, 6 waves (one per head).
//   phase 1: stage x fp32 -> bf16 (49x192 -> 64x200 padded) + mask bias in LDS
//   phase 2a: Q,K GEMM (swapped operands mfma(W,X) -> Q^T/K^T C-layout),
//             collapsed to NATURAL-order bf16 fragments via quad-shuffle xpose
//             (hardware-proven path; keeps S and P bit-exact with v4/v5).
//   phase 2b: V GEMM (normal operands) -> vf kept IN REGISTERS, dual-packed
//             (NEW: no vt LDS round-trip).
//   phase 4+5 per q-tile nt: S slice = mfma32(kf,qf) natural; masked softmax
//             (lane-local q-rows, 2 shfl_xor); pf = cvt8(sr pairs) dual-packed;
//             O slice = mfma32(pf, vf); write to separate LDS O-region.
//   phase 6: barrier; cooperative projection GEMM from O-region + bias, store.
//
// Dual-packing (PV only): a K=32 fragment's 8 elems sit at slots quad*8+e.
// Packing elems 0-3 from token sub-tile 2j (coord quad*4+e) and 4-7 from
// sub-tile 2j+1 is a bijection onto the 64 tokens across j=0,1; packing BOTH
// pf and vf identically makes the contraction exact for ANY hardware slot
// map (phase-2 correctness forces sigma_A == sigma_B).
//
// v9 rationale: v8 (dual-packed QK^T AND PV) measured absmax 2.8e-3 vs
// threshold 1.94e-3 -- algebra checks out, so the regression is either the
// reordered in-MFMA summation shifting bf16 rounding realizations (v1-v5,
// five bit-identical pipelines, all sat at exactly 4.88e-4) or a subtle
// QK-side issue. v9 restores bit-exact natural order for QK^T/softmax/P and
// keeps the provably-symmetric dual-pack only for PV. Structural wins kept:
// no vt LDS, no P LDS, 8 of 16 xposes deleted, 2 barriers (was 3).
//
// Weights repacked each call fp32 -> bf16 in B-fragment-contiguous layout:
// wp[(kt*COLS + col)*32 + kk] = w[(kt*32+kk)*COLS + col].

typedef __attribute__((ext_vector_type(8))) short short8;
typedef __attribute__((ext_vector_type(4))) float f32x4;

#define SCALE 0.17677669529663687f   // 32^-0.5

__device__ __forceinline__ unsigned short f2bf(float x) {
    union { float f; unsigned int i; } v; v.f = x;
    return (unsigned short)((v.i + 0x7FFFu + ((v.i >> 16) & 1u)) >> 16);
}

// packed f32x2 -> bf16x2 (RNE), 1 instr
__device__ __forceinline__ unsigned int pkbf(float lo, float hi) {
    unsigned int r;
    asm("v_cvt_pk_bf16_f32 %0, %1, %2" : "=v"(r) : "v"(lo), "v"(hi));
    return r;
}

// two C-layout f32x4 sub-tiles -> one dual-packed K=32 bf16 fragment
__device__ __forceinline__ short8 cvt8(f32x4 lo, f32x4 hi) {
    union { short8 s; unsigned int u[4]; } r;
    r.u[0] = pkbf(lo[0], lo[1]);
    r.u[1] = pkbf(lo[2], lo[3]);
    r.u[2] = pkbf(hi[0], hi[1]);
    r.u[3] = pkbf(hi[2], hi[3]);
    return r.s;
}

__device__ __forceinline__ f32x4 addb(f32x4 v, float b) {
    v[0] += b; v[1] += b; v[2] += b; v[3] += b;
    return v;
}

// C-layout pair (two 16-row tiles: tlo = dims/k 0..15, thi = 16..31) ->
// NATURAL-order A/B MFMA fragment (k = quad*8+e). dst lane (quad,l16) elem e
// from src lane ((quad&1)*2 + (e>>2))*16 + l16, tile selected by quad>>1.
__device__ __forceinline__ short8 xpose(f32x4 tlo, f32x4 thi, int srcA, bool hi) {
    unsigned int pl0 = pkbf(tlo[0], tlo[1]);
    unsigned int pl1 = pkbf(tlo[2], tlo[3]);
    unsigned int ph0 = pkbf(thi[0], thi[1]);
    unsigned int ph1 = pkbf(thi[2], thi[3]);
    unsigned int a0 = (unsigned int)__shfl((int)pl0, srcA);
    unsigned int b0 = (unsigned int)__shfl((int)ph0, srcA);
    unsigned int a1 = (unsigned int)__shfl((int)pl1, srcA);
    unsigned int b1 = (unsigned int)__shfl((int)ph1, srcA);
    unsigned int a2 = (unsigned int)__shfl((int)pl0, srcA + 16);
    unsigned int b2 = (unsigned int)__shfl((int)ph0, srcA + 16);
    unsigned int a3 = (unsigned int)__shfl((int)pl1, srcA + 16);
    unsigned int b3 = (unsigned int)__shfl((int)ph1, srcA + 16);
    union { short8 s8; unsigned int u[4]; } f;
    f.u[0] = hi ? b0 : a0;
    f.u[1] = hi ? b1 : a1;
    f.u[2] = hi ? b2 : a2;
    f.u[3] = hi ? b3 : a3;
    return f.s8;
}

__global__ void repack_kernel(const float* __restrict__ wqkv,
                              const float* __restrict__ wproj,
                              unsigned short* __restrict__ wq_pack,
                              unsigned short* __restrict__ wp_pack) {
    int idx = blockIdx.x * 256 + threadIdx.x;
    if (idx < 6 * 576 * 32) {
        int kk  = idx & 31;
        int col = (idx >> 5) % 576;
        int kt  = idx / (576 * 32);
        wq_pack[idx] = f2bf(wqkv[(kt * 32 + kk) * 576 + col]);
    } else {
        int j = idx - 6 * 576 * 32;
        if (j < 6 * 192 * 32) {
            int kk  = j & 31;
            int col = (j >> 5) % 192;
            int kt  = j / (192 * 32);
            wp_pack[j] = f2bf(wproj[(kt * 32 + kk) * 192 + col]);
        }
    }
}

__global__ __launch_bounds__(384)
void win_attn_kernel(const float* __restrict__ x,
                     const int* __restrict__ mask,
                     const float* __restrict__ bqkv,
                     const float* __restrict__ bproj,
                     const unsigned short* __restrict__ wq,
                     const unsigned short* __restrict__ wpj,
                     float* __restrict__ out) {
    // region: [0..12800)      x tile 64x200 bf16 (phases 1-2)
    //         [12800..25600)  O_all 64x200 bf16 (phases 5-6), DISJOINT from x
    __shared__ __align__(16) unsigned short region[25600];
    __shared__ __align__(16) float mbias[64];

    const int b    = blockIdx.x;
    const int tid  = threadIdx.x;
    const int lane = tid & 63;
    const int h    = tid >> 6;      // wave index == head
    const int quad = lane >> 4;
    const int l16  = lane & 15;

    // ---------------- phase 1: stage x (fp32 -> bf16), pad, mask bias -----
    const float* xb = x + (size_t)b * 9408;
    for (int i4 = tid; i4 < 2352; i4 += 384) {   // 9408 elems / 4
        int flat = i4 * 4;
        int n = flat / 192, c = flat % 192;      // 192 % 4 == 0: no row cross
        float4 v = *(const float4*)(const void*)&xb[flat];
        uint2 pk;
        pk.x = pkbf(v.x, v.y);
        pk.y = pkbf(v.z, v.w);
        *(uint2*)(void*)&region[n * 200 + c] = pk;
    }
    if (tid < 375) {                              // zero rows 49..63 (15*200)
        uint4 z = {0u, 0u, 0u, 0u};
        *(uint4*)(void*)&region[9800 + tid * 8] = z;
    }
    if (tid < 64)
        mbias[tid] = (tid < 49 && mask[b * 49 + tid] != 0) ? 0.0f : -1e30f;
    __syncthreads();

    const int  srcA = ((lane & 16) << 1) | l16;   // ((quad&1)*2)*16 + l16
    const bool hiq  = (lane & 32) != 0;           // quad>>1

    int colb[6];
    #pragma unroll
    for (int t = 0; t < 6; ++t) colb[t] = (t >> 1) * 192 + h * 32 + (t & 1) * 16;

    // ---------------- phase 2a: Q,K GEMM (swapped operands) ---------------
    // acc[t][nt]: lane holds Y[token=nt*16+l16][dim = colb[t]+quad*4+r]
    short8 qf[4], kf[4];
    {
        f32x4 acc[4][4];
        #pragma unroll
        for (int t = 0; t < 4; ++t)
            #pragma unroll
            for (int mt = 0; mt < 4; ++mt)
                acc[t][mt] = (f32x4){0.f, 0.f, 0.f, 0.f};

        #pragma unroll
        for (int kt = 0; kt < 6; ++kt) {
            short8 af[4];
            #pragma unroll
            for (int mt = 0; mt < 4; ++mt)
                af[mt] = *(const short8*)(const void*)
                         &region[(mt * 16 + l16) * 200 + kt * 32 + quad * 8];
            #pragma unroll
            for (int t = 0; t < 4; ++t) {
                short8 bw = *(const short8*)(const void*)
                            &wq[(size_t)(kt * 576 + colb[t] + l16) * 32 + quad * 8];
                #pragma unroll
                for (int mt = 0; mt < 4; ++mt)
                    acc[t][mt] = __builtin_amdgcn_mfma_f32_16x16x32_bf16(
                                     bw, af[mt], acc[t][mt], 0, 0, 0);
            }
        }
        // bias: outcol = colb[t] + quad*4 + r
        #pragma unroll
        for (int t = 0; t < 4; ++t) {
            f32x4 bq = *(const f32x4*)(const void*)&bqkv[colb[t] + quad * 4];
            #pragma unroll
            for (int nt = 0; nt < 4; ++nt)
                #pragma unroll
                for (int r = 0; r < 4; ++r)
                    acc[t][nt][r] += bq[r];
        }
        // collapse to NATURAL bf16 fragments (proven xpose path)
        #pragma unroll
        for (int nt = 0; nt < 4; ++nt) {
            qf[nt] = xpose(acc[0][nt], acc[1][nt], srcA, hiq);
            kf[nt] = xpose(acc[2][nt], acc[3][nt], srcA, hiq);
        }
    }

    // ---------------- phase 2b: V GEMM -> dual-packed register frags ------
    // vf[t][j]: elems 0-3 = token (2j)*16+quad*4+e, 4-7 = (2j+1)*16+quad*4+e'
    short8 vf[2][2];
    {
        f32x4 accv[2][4];
        #pragma unroll
        for (int t = 0; t < 2; ++t)
            #pragma unroll
            for (int mt = 0; mt < 4; ++mt)
                accv[t][mt] = (f32x4){0.f, 0.f, 0.f, 0.f};

        #pragma unroll
        for (int kt = 0; kt < 6; ++kt) {
            short8 af[4];
            #pragma unroll
            for (int mt = 0; mt < 4; ++mt)
                af[mt] = *(const short8*)(const void*)
                         &region[(mt * 16 + l16) * 200 + kt * 32 + quad * 8];
            #pragma unroll
            for (int t = 0; t < 2; ++t) {
                short8 bw = *(const short8*)(const void*)
                            &wq[(size_t)(kt * 576 + colb[4 + t] + l16) * 32 + quad * 8];
                #pragma unroll
                for (int mt = 0; mt < 4; ++mt)
                    accv[t][mt] = __builtin_amdgcn_mfma_f32_16x16x32_bf16(
                                      af[mt], bw, accv[t][mt], 0, 0, 0);
            }
        }
        #pragma unroll
        for (int t = 0; t < 2; ++t) {
            float bv = bqkv[colb[4 + t] + l16];
            #pragma unroll
            for (int j = 0; j < 2; ++j)
                vf[t][j] = cvt8(addb(accv[t][2 * j], bv),
                                addb(accv[t][2 * j + 1], bv));
        }
    }

    // ---------------- phase 4+5: per q-tile S, softmax, O -----------------
    f32x4 mb4[4];
    #pragma unroll
    for (int mt = 0; mt < 4; ++mt)
        mb4[mt] = *(const f32x4*)(const void*)&mbias[mt * 16 + quad * 4];

    unsigned short* ob = &region[12800];
    #pragma unroll
    for (int nt = 0; nt < 4; ++nt) {
        // sr[mt]: lane holds S[q=nt*16+l16][k=mt*16+quad*4+r]
        f32x4 sr[4];
        #pragma unroll
        for (int mt = 0; mt < 4; ++mt) {
            sr[mt] = (f32x4){0.f, 0.f, 0.f, 0.f};
            sr[mt] = __builtin_amdgcn_mfma_f32_16x16x32_bf16(
                         kf[mt], qf[nt], sr[mt], 0, 0, 0);
        }
        float pm[4];
        #pragma unroll
        for (int mt = 0; mt < 4; ++mt) {
            #pragma unroll
            for (int r = 0; r < 4; ++r)
                sr[mt][r] = sr[mt][r] * SCALE + mb4[mt][r];
            pm[mt] = fmaxf(fmaxf(sr[mt][0], sr[mt][1]),
                           fmaxf(sr[mt][2], sr[mt][3]));
        }
        float mx = fmaxf(fmaxf(pm[0], pm[1]), fmaxf(pm[2], pm[3]));
        mx = fmaxf(mx, __shfl_xor(mx, 16));
        mx = fmaxf(mx, __shfl_xor(mx, 32));
        float ps[4];
        #pragma unroll
        for (int mt = 0; mt < 4; ++mt) {
            #pragma unroll
            for (int r = 0; r < 4; ++r)
                sr[mt][r] = __expf(sr[mt][r] - mx);
            ps[mt] = (sr[mt][0] + sr[mt][1]) + (sr[mt][2] + sr[mt][3]);
        }
        float sum = (ps[0] + ps[1]) + (ps[2] + ps[3]);
        sum += __shfl_xor(sum, 16);
        sum += __shfl_xor(sum, 32);
        float inv = 1.0f / sum;
        #pragma unroll
        for (int mt = 0; mt < 4; ++mt)
            #pragma unroll
            for (int r = 0; r < 4; ++r)
                sr[mt][r] *= inv;

        // pf[j]: P A-fragment (m=q=l16), token pair (2j,2j+1) dual-packed
        short8 pf[2];
        pf[0] = cvt8(sr[0], sr[1]);
        pf[1] = cvt8(sr[2], sr[3]);

        // O slice: on[t] (C-layout [q=nt*16+quad*4+r][d=t*16+l16])
        f32x4 on[2];
        #pragma unroll
        for (int t = 0; t < 2; ++t)
            on[t] = (f32x4){0.f, 0.f, 0.f, 0.f};
        #pragma unroll
        for (int j = 0; j < 2; ++j)
            #pragma unroll
            for (int t = 0; t < 2; ++t)
                on[t] = __builtin_amdgcn_mfma_f32_16x16x32_bf16(
                            pf[j], vf[t][j], on[t], 0, 0, 0);

        // write O slice to O-region (disjoint from x-tile: no pre-barrier)
        #pragma unroll
        for (int t = 0; t < 2; ++t)
            #pragma unroll
            for (int r = 0; r < 4; ++r)
                ob[(nt * 16 + quad * 4 + r) * 200 + h * 32 + t * 16 + l16]
                    = f2bf(on[t][r]);
    }

    __syncthreads();   // all heads' O visible

    // ---------------- phase 6: projection GEMM + bias + fp32 store -------
    f32x4 po[2][4];
    #pragma unroll
    for (int nt = 0; nt < 2; ++nt)
        #pragma unroll
        for (int mt = 0; mt < 4; ++mt)
            po[nt][mt] = (f32x4){0.f, 0.f, 0.f, 0.f};

    #pragma unroll
    for (int kt = 0; kt < 6; ++kt) {
        short8 ao[4];
        #pragma unroll
        for (int mt = 0; mt < 4; ++mt)
            ao[mt] = *(const short8*)(const void*)
                     &ob[(mt * 16 + l16) * 200 + kt * 32 + quad * 8];
        #pragma unroll
        for (int nt = 0; nt < 2; ++nt) {
            int col = h * 32 + nt * 16 + l16;
            short8 bw = *(const short8*)(const void*)
                        &wpj[(size_t)(kt * 192 + col) * 32 + quad * 8];
            #pragma unroll
            for (int mt = 0; mt < 4; ++mt)
                po[nt][mt] = __builtin_amdgcn_mfma_f32_16x16x32_bf16(
                                 ao[mt], bw, po[nt][mt], 0, 0, 0);
        }
    }

    #pragma unroll
    for (int nt = 0; nt < 2; ++nt) {
        int col = h * 32 + nt * 16 + l16;
        float bv = bproj[col];
        #pragma unroll
        for (int mt = 0; mt < 4; ++mt)
            #pragma unroll
            for (int r = 0; r < 4; ++r) {
                int row = mt * 16 + quad * 4 + r;
                if (row < 49)
                    out[(size_t)b * 9408 + row * 192 + col] = po[nt][mt][r] + bv;
            }
    }
}

extern "C" void kernel_launch(void* const* d_in, const int* in_sizes, int n_in,
                              void* d_out, int out_size, void* d_ws, size_t ws_size,
                              hipStream_t stream) {
    const float* x      = (const float*)d_in[0];
    const int*   mask   = (const int*)d_in[1];
    const float* w_qkv  = (const float*)d_in[2];
    const float* b_qkv  = (const float*)d_in[3];
    const float* w_proj = (const float*)d_in[4];
    const float* b_proj = (const float*)d_in[5];
    float*       out    = (float*)d_out;

    unsigned short* wq_pack = (unsigned short*)d_ws;          // 110592 elems
    unsigned short* wp_pack = wq_pack + 110592;               //  36864 elems

    repack_kernel<<<(110592 + 36864 + 255) / 256, 256, 0, stream>>>(
        w_qkv, w_proj, wq_pack, wp_pack);
    win_attn_kernel<<<8192, 384, 0, stream>>>(x, mask, b_qkv, b_proj,
                                              wq_pack, wp_pack, out);
}

// Round 11
// 819.061 us; speedup vs baseline: 1.6722x; 1.0183x over previous
//
#include <hip/hip_runtime.h>

// Fused windowed multi-head attention for MI355X (gfx950).
// B=8192 windows, N=49 tokens, C=192, H=6 heads, HD=32.
// Inputs/outputs are FP32 (per reference); mask int32. Interior compute bf16 MFMA.
//
// Structure (v10): 1 block per window, 6 waves (one per head).
//   phase 1: stage x fp32 -> bf16 (49x192 -> 64x200 padded) + mask bias in LDS;
//            kt=0 weight fragments preloaded BEFORE the barrier (L2 latency
//            hidden under barrier wait; compiler can't hoist across sync).
//   phase 2: MERGED QKV GEMM -- one x-fragment read per kt feeds all 6 column
//            tiles (v9 split 2a/2b re-read the same 24 b128/wave twice; the
//            merge cuts block LDS reads 432->288). q,k swapped mfma(W,X) ->
//            Q^T/K^T C-layout; v normal mfma(X,W).
//            Collapse: qf/kf via NATURAL-order quad-shuffle xpose (keeps S
//            bit-exact -- v8 showed reordered QK^T flips P bf16 roundings ->
//            2.8e-3 fail); vf dual-packed in registers (order-insensitive
//            below the P-quantization floor, v9-verified).
//   phase 4+5 per q-tile nt: S slice = mfma32(kf,qf); masked softmax
//            (lane-local q-rows, 2 shfl_xor); pf = cvt8(sr pairs); O slice =
//            mfma32(pf, vf); write to separate LDS O-region.
//   phase 6: wpj fragments preloaded before the barrier; cooperative
//            projection GEMM from O-region + bias, fp32 store.
//
// Perf model (v5/v9 evidence): 2x TLP at fixed per-CU work = zero gain ->
// a per-CU shared resource scales with work; LDS pipe is the only one near
// 50% (432 b128 reads x ~16cyc + 384 bpermute per block). v10 attacks read
// volume and barrier-exposed global-load latency.
//
// Weights repacked each call fp32 -> bf16 in B-fragment-contiguous layout:
// wp[(kt*COLS + col)*32 + kk] = w[(kt*32+kk)*COLS + col].

typedef __attribute__((ext_vector_type(8))) short short8;
typedef __attribute__((ext_vector_type(4))) float f32x4;

#define SCALE 0.17677669529663687f   // 32^-0.5

__device__ __forceinline__ unsigned short f2bf(float x) {
    union { float f; unsigned int i; } v; v.f = x;
    return (unsigned short)((v.i + 0x7FFFu + ((v.i >> 16) & 1u)) >> 16);
}

// packed f32x2 -> bf16x2 (RNE), 1 instr
__device__ __forceinline__ unsigned int pkbf(float lo, float hi) {
    unsigned int r;
    asm("v_cvt_pk_bf16_f32 %0, %1, %2" : "=v"(r) : "v"(lo), "v"(hi));
    return r;
}

// two C-layout f32x4 sub-tiles -> one dual-packed K=32 bf16 fragment
__device__ __forceinline__ short8 cvt8(f32x4 lo, f32x4 hi) {
    union { short8 s; unsigned int u[4]; } r;
    r.u[0] = pkbf(lo[0], lo[1]);
    r.u[1] = pkbf(lo[2], lo[3]);
    r.u[2] = pkbf(hi[0], hi[1]);
    r.u[3] = pkbf(hi[2], hi[3]);
    return r.s;
}

__device__ __forceinline__ f32x4 addb(f32x4 v, float b) {
    v[0] += b; v[1] += b; v[2] += b; v[3] += b;
    return v;
}

// C-layout pair (two 16-row tiles: tlo = dims/k 0..15, thi = 16..31) ->
// NATURAL-order A/B MFMA fragment (k = quad*8+e). dst lane (quad,l16) elem e
// from src lane ((quad&1)*2 + (e>>2))*16 + l16, tile selected by quad>>1.
__device__ __forceinline__ short8 xpose(f32x4 tlo, f32x4 thi, int srcA, bool hi) {
    unsigned int pl0 = pkbf(tlo[0], tlo[1]);
    unsigned int pl1 = pkbf(tlo[2], tlo[3]);
    unsigned int ph0 = pkbf(thi[0], thi[1]);
    unsigned int ph1 = pkbf(thi[2], thi[3]);
    unsigned int a0 = (unsigned int)__shfl((int)pl0, srcA);
    unsigned int b0 = (unsigned int)__shfl((int)ph0, srcA);
    unsigned int a1 = (unsigned int)__shfl((int)pl1, srcA);
    unsigned int b1 = (unsigned int)__shfl((int)ph1, srcA);
    unsigned int a2 = (unsigned int)__shfl((int)pl0, srcA + 16);
    unsigned int b2 = (unsigned int)__shfl((int)ph0, srcA + 16);
    unsigned int a3 = (unsigned int)__shfl((int)pl1, srcA + 16);
    unsigned int b3 = (unsigned int)__shfl((int)ph1, srcA + 16);
    union { short8 s8; unsigned int u[4]; } f;
    f.u[0] = hi ? b0 : a0;
    f.u[1] = hi ? b1 : a1;
    f.u[2] = hi ? b2 : a2;
    f.u[3] = hi ? b3 : a3;
    return f.s8;
}

__global__ void repack_kernel(const float* __restrict__ wqkv,
                              const float* __restrict__ wproj,
                              unsigned short* __restrict__ wq_pack,
                              unsigned short* __restrict__ wp_pack) {
    int idx = blockIdx.x * 256 + threadIdx.x;
    if (idx < 6 * 576 * 32) {
        int kk  = idx & 31;
        int col = (idx >> 5) % 576;
        int kt  = idx / (576 * 32);
        wq_pack[idx] = f2bf(wqkv[(kt * 32 + kk) * 576 + col]);
    } else {
        int j = idx - 6 * 576 * 32;
        if (j < 6 * 192 * 32) {
            int kk  = j & 31;
            int col = (j >> 5) % 192;
            int kt  = j / (192 * 32);
            wp_pack[j] = f2bf(wproj[(kt * 32 + kk) * 192 + col]);
        }
    }
}

__global__ __launch_bounds__(384)
void win_attn_kernel(const float* __restrict__ x,
                     const int* __restrict__ mask,
                     const float* __restrict__ bqkv,
                     const float* __restrict__ bproj,
                     const unsigned short* __restrict__ wq,
                     const unsigned short* __restrict__ wpj,
                     float* __restrict__ out) {
    // region: [0..12800)      x tile 64x200 bf16 (phases 1-2)
    //         [12800..25600)  O_all 64x200 bf16 (phases 5-6), DISJOINT from x
    __shared__ __align__(16) unsigned short region[25600];
    __shared__ __align__(16) float mbias[64];

    const int b    = blockIdx.x;
    const int tid  = threadIdx.x;
    const int lane = tid & 63;
    const int h    = tid >> 6;      // wave index == head
    const int quad = lane >> 4;
    const int l16  = lane & 15;

    int colb[6];
    #pragma unroll
    for (int t = 0; t < 6; ++t) colb[t] = (t >> 1) * 192 + h * 32 + (t & 1) * 16;

    // ---------------- phase 1: stage x (fp32 -> bf16), pad, mask bias -----
    const float* xb = x + (size_t)b * 9408;
    for (int i4 = tid; i4 < 2352; i4 += 384) {   // 9408 elems / 4
        int flat = i4 * 4;
        int n = flat / 192, c = flat % 192;      // 192 % 4 == 0: no row cross
        float4 v = *(const float4*)(const void*)&xb[flat];
        uint2 pk;
        pk.x = pkbf(v.x, v.y);
        pk.y = pkbf(v.z, v.w);
        *(uint2*)(void*)&region[n * 200 + c] = pk;
    }
    if (tid < 375) {                              // zero rows 49..63 (15*200)
        uint4 z = {0u, 0u, 0u, 0u};
        *(uint4*)(void*)&region[9800 + tid * 8] = z;
    }
    if (tid < 64)
        mbias[tid] = (tid < 49 && mask[b * 49 + tid] != 0) ? 0.0f : -1e30f;

    // preload kt=0 weight fragments (independent of LDS staging; issued
    // before the barrier so L2 latency hides under the barrier wait)
    short8 bw0[6];
    #pragma unroll
    for (int t = 0; t < 6; ++t)
        bw0[t] = *(const short8*)(const void*)
                 &wq[(size_t)(colb[t] + l16) * 32 + quad * 8];

    __syncthreads();

    const int  srcA = ((lane & 16) << 1) | l16;   // ((quad&1)*2)*16 + l16
    const bool hiq  = (lane & 32) != 0;           // quad>>1

    // ---------------- phase 2: MERGED QKV GEMM ----------------------------
    // t=0..3 (q,k): swapped -> acc[t][nt]: lane holds
    //   Y[token=nt*16+l16][dim = colb[t]+quad*4+r]  (Y=Q for t<2, K for t<4)
    // t=4..5 (v): normal -> acc[t][mt]: lane holds
    //   V[token=mt*16+quad*4+r][dim=(t-4)*16+l16]
    f32x4 acc[6][4];
    #pragma unroll
    for (int t = 0; t < 6; ++t)
        #pragma unroll
        for (int mt = 0; mt < 4; ++mt)
            acc[t][mt] = (f32x4){0.f, 0.f, 0.f, 0.f};

    #pragma unroll
    for (int kt = 0; kt < 6; ++kt) {
        short8 af[4];
        #pragma unroll
        for (int mt = 0; mt < 4; ++mt)
            af[mt] = *(const short8*)(const void*)
                     &region[(mt * 16 + l16) * 200 + kt * 32 + quad * 8];
        #pragma unroll
        for (int t = 0; t < 6; ++t) {
            short8 bw = (kt == 0) ? bw0[t]
                      : *(const short8*)(const void*)
                        &wq[(size_t)(kt * 576 + colb[t] + l16) * 32 + quad * 8];
            #pragma unroll
            for (int mt = 0; mt < 4; ++mt) {
                if (t < 4)
                    acc[t][mt] = __builtin_amdgcn_mfma_f32_16x16x32_bf16(
                                     bw, af[mt], acc[t][mt], 0, 0, 0);
                else
                    acc[t][mt] = __builtin_amdgcn_mfma_f32_16x16x32_bf16(
                                     af[mt], bw, acc[t][mt], 0, 0, 0);
            }
        }
    }

    // bias + collapse: qf/kf NATURAL order (bit-exact S), vf dual-packed.
    short8 qf[4], kf[4], vf[2][2];
    {
        f32x4 bq0 = *(const f32x4*)(const void*)&bqkv[colb[0] + quad * 4];
        f32x4 bq1 = *(const f32x4*)(const void*)&bqkv[colb[1] + quad * 4];
        f32x4 bk0 = *(const f32x4*)(const void*)&bqkv[colb[2] + quad * 4];
        f32x4 bk1 = *(const f32x4*)(const void*)&bqkv[colb[3] + quad * 4];
        #pragma unroll
        for (int nt = 0; nt < 4; ++nt) {
            qf[nt] = xpose(acc[0][nt] + bq0, acc[1][nt] + bq1, srcA, hiq);
            kf[nt] = xpose(acc[2][nt] + bk0, acc[3][nt] + bk1, srcA, hiq);
        }
        float bv0 = bqkv[colb[4] + l16];
        float bv1 = bqkv[colb[5] + l16];
        #pragma unroll
        for (int j = 0; j < 2; ++j) {
            vf[0][j] = cvt8(addb(acc[4][2 * j], bv0), addb(acc[4][2 * j + 1], bv0));
            vf[1][j] = cvt8(addb(acc[5][2 * j], bv1), addb(acc[5][2 * j + 1], bv1));
        }
    }

    // ---------------- phase 4+5: per q-tile S, softmax, O -----------------
    f32x4 mb4[4];
    #pragma unroll
    for (int mt = 0; mt < 4; ++mt)
        mb4[mt] = *(const f32x4*)(const void*)&mbias[mt * 16 + quad * 4];

    unsigned short* ob = &region[12800];
    #pragma unroll
    for (int nt = 0; nt < 4; ++nt) {
        // sr[mt]: lane holds S[q=nt*16+l16][k=mt*16+quad*4+r]
        f32x4 sr[4];
        #pragma unroll
        for (int mt = 0; mt < 4; ++mt) {
            sr[mt] = (f32x4){0.f, 0.f, 0.f, 0.f};
            sr[mt] = __builtin_amdgcn_mfma_f32_16x16x32_bf16(
                         kf[mt], qf[nt], sr[mt], 0, 0, 0);
        }
        float pm[4];
        #pragma unroll
        for (int mt = 0; mt < 4; ++mt) {
            #pragma unroll
            for (int r = 0; r < 4; ++r)
                sr[mt][r] = sr[mt][r] * SCALE + mb4[mt][r];
            pm[mt] = fmaxf(fmaxf(sr[mt][0], sr[mt][1]),
                           fmaxf(sr[mt][2], sr[mt][3]));
        }
        float mx = fmaxf(fmaxf(pm[0], pm[1]), fmaxf(pm[2], pm[3]));
        mx = fmaxf(mx, __shfl_xor(mx, 16));
        mx = fmaxf(mx, __shfl_xor(mx, 32));
        float ps[4];
        #pragma unroll
        for (int mt = 0; mt < 4; ++mt) {
            #pragma unroll
            for (int r = 0; r < 4; ++r)
                sr[mt][r] = __expf(sr[mt][r] - mx);
            ps[mt] = (sr[mt][0] + sr[mt][1]) + (sr[mt][2] + sr[mt][3]);
        }
        float sum = (ps[0] + ps[1]) + (ps[2] + ps[3]);
        sum += __shfl_xor(sum, 16);
        sum += __shfl_xor(sum, 32);
        float inv = 1.0f / sum;
        #pragma unroll
        for (int mt = 0; mt < 4; ++mt)
            #pragma unroll
            for (int r = 0; r < 4; ++r)
                sr[mt][r] *= inv;

        // pf[j]: P A-fragment (m=q=l16), token pair (2j,2j+1) dual-packed
        short8 pf[2];
        pf[0] = cvt8(sr[0], sr[1]);
        pf[1] = cvt8(sr[2], sr[3]);

        // O slice: on[t] (C-layout [q=nt*16+quad*4+r][d=t*16+l16])
        f32x4 on[2];
        #pragma unroll
        for (int t = 0; t < 2; ++t)
            on[t] = (f32x4){0.f, 0.f, 0.f, 0.f};
        #pragma unroll
        for (int j = 0; j < 2; ++j)
            #pragma unroll
            for (int t = 0; t < 2; ++t)
                on[t] = __builtin_amdgcn_mfma_f32_16x16x32_bf16(
                            pf[j], vf[t][j], on[t], 0, 0, 0);

        // write O slice to O-region (disjoint from x-tile: no pre-barrier)
        #pragma unroll
        for (int t = 0; t < 2; ++t)
            #pragma unroll
            for (int r = 0; r < 4; ++r)
                ob[(nt * 16 + quad * 4 + r) * 200 + h * 32 + t * 16 + l16]
                    = f2bf(on[t][r]);
    }

    // preload ALL projection-weight fragments before the barrier (regs are
    // free here: acc/qf/kf/vf dead or dying; latency hides under barrier)
    short8 bwp[6][2];
    #pragma unroll
    for (int kt = 0; kt < 6; ++kt)
        #pragma unroll
        for (int nt = 0; nt < 2; ++nt)
            bwp[kt][nt] = *(const short8*)(const void*)
                          &wpj[(size_t)(kt * 192 + h * 32 + nt * 16 + l16) * 32
                               + quad * 8];

    __syncthreads();   // all heads' O visible

    // ---------------- phase 6: projection GEMM + bias + fp32 store -------
    f32x4 po[2][4];
    #pragma unroll
    for (int nt = 0; nt < 2; ++nt)
        #pragma unroll
        for (int mt = 0; mt < 4; ++mt)
            po[nt][mt] = (f32x4){0.f, 0.f, 0.f, 0.f};

    #pragma unroll
    for (int kt = 0; kt < 6; ++kt) {
        short8 ao[4];
        #pragma unroll
        for (int mt = 0; mt < 4; ++mt)
            ao[mt] = *(const short8*)(const void*)
                     &ob[(mt * 16 + l16) * 200 + kt * 32 + quad * 8];
        #pragma unroll
        for (int nt = 0; nt < 2; ++nt)
            #pragma unroll
            for (int mt = 0; mt < 4; ++mt)
                po[nt][mt] = __builtin_amdgcn_mfma_f32_16x16x32_bf16(
                                 ao[mt], bwp[kt][nt], po[nt][mt], 0, 0, 0);
    }

    #pragma unroll
    for (int nt = 0; nt < 2; ++nt) {
        int col = h * 32 + nt * 16 + l16;
        float bv = bproj[col];
        #pragma unroll
        for (int mt = 0; mt < 4; ++mt)
            #pragma unroll
            for (int r = 0; r < 4; ++r) {
                int row = mt * 16 + quad * 4 + r;
                if (row < 49)
                    out[(size_t)b * 9408 + row * 192 + col] = po[nt][mt][r] + bv;
            }
    }
}

extern "C" void kernel_launch(void* const* d_in, const int* in_sizes, int n_in,
                              void* d_out, int out_size, void* d_ws, size_t ws_size,
                              hipStream_t stream) {
    const float* x      = (const float*)d_in[0];
    const int*   mask   = (const int*)d_in[1];
    const float* w_qkv  = (const float*)d_in[2];
    const float* b_qkv  = (const float*)d_in[3];
    const float* w_proj = (const float*)d_in[4];
    const float* b_proj = (const float*)d_in[5];
    float*       out    = (float*)d_out;

    unsigned short* wq_pack = (unsigned short*)d_ws;          // 110592 elems
    unsigned short* wp_pack = wq_pack + 110592;               //  36864 elems

    repack_kernel<<<(110592 + 36864 + 255) / 256, 256, 0, stream>>>(
        w_qkv, w_proj, wq_pack, wp_pack);
    win_attn_kernel<<<8192, 384, 0, stream>>>(x, mask, b_qkv, b_proj,
                                              wq_pack, wp_pack, out);
}